// Round 6
// baseline (533.872 us; speedup 1.0000x reference)
//
#include <hip/hip_runtime.h>
#include <hip/hip_fp16.h>

#define N_NODES 100000
#define N_EDGES 1250000
#define D 64

#define BSHIFT 9
#define BUCKETS 196          // ceil(100000 / 512)
#define CAP 8192             // tmp capacity per bucket (mean 6378, +22 sigma)
#define CHUNK 4096           // edges per bucketA block
#define PA_BLOCKS ((N_EDGES + CHUNK - 1) / CHUNK)   // 306
#define LCAP 64              // LDS list cap per bucket per chunk (mean 21)

typedef long long ll;

// ---------- init: cursor[b] = b*CAP; zero-pad srt tail ----------
__global__ void init_kernel(int* __restrict__ cursor, int* __restrict__ srt) {
    int t = threadIdx.x;
    if (t < BUCKETS) cursor[t] = t * CAP;
    if (t < 8) srt[N_EDGES + t] = 0;
}

// ---------- fp32 -> fp16 cast (x -> xb), float4 granularity ----------
__global__ void cast_kernel(const float* __restrict__ in, __half* __restrict__ out) {
    int i = blockIdx.x * 256 + threadIdx.x;
    if (i < N_NODES * D / 4) {
        float4 v = ((const float4*)in)[i];
        __half2 a = __floats2half2_rn(v.x, v.y);
        __half2 b = __floats2half2_rn(v.z, v.w);
        uint2 u;
        u.x = *(const unsigned int*)&a;
        u.y = *(const unsigned int*)&b;
        ((uint2*)out)[i] = u;
    }
}

// ---------- pass A: bin edges into 196 coarse buckets, coalesced flushes ----------
__global__ __launch_bounds__(256) void bucketA_kernel(const int* __restrict__ src,
                                                      const int* __restrict__ dst,
                                                      int* __restrict__ cursor,
                                                      int* __restrict__ tmp) {
    __shared__ int lcnt[BUCKETS];
    __shared__ int list[BUCKETS * LCAP];   // ~50 KB
    int tid = threadIdx.x;
    for (int b = tid; b < BUCKETS; b += 256) lcnt[b] = 0;
    __syncthreads();

    int base = blockIdx.x * CHUNK;
    int nE = min(CHUNK, N_EDGES - base);
    for (int i = tid; i < nE; i += 256) {
        int e = base + i;
        int s = src[e], d = dst[e];
        int b = d >> BSHIFT;
        int p = atomicAdd(&lcnt[b], 1);             // LDS atomic, cheap
        list[b * LCAP + p] = s | ((d & 511) << 17); // src:17b, dstLow:9b
    }
    __syncthreads();

    // wave-cooperative flush: one global atomic per (wave, bucket),
    // lanes write the run in parallel (coalesced)
    int wave = tid >> 6, lane = tid & 63;
    for (int b = wave; b < BUCKETS; b += 4) {
        int c = lcnt[b];                   // wave-uniform
        if (c > 0) {
            int gb = 0;
            if (lane == 0) gb = atomicAdd(&cursor[b], c);
            gb = __shfl(gb, 0);
            for (int k = lane; k < c; k += 64) tmp[gb + k] = list[b * LCAP + k];
        }
    }
}

// ---------- tiny scan: bucket bases from cursor counts ----------
__global__ void scanSmall_kernel(const int* __restrict__ cursor, int* __restrict__ bbase) {
    __shared__ int s[256];
    int tid = threadIdx.x;
    int x = (tid < BUCKETS) ? (cursor[tid] - tid * CAP) : 0;
    s[tid] = x;
    __syncthreads();
    for (int off = 1; off < 256; off <<= 1) {
        int v = (tid >= off) ? s[tid - off] : 0;
        __syncthreads();
        s[tid] += v;
        __syncthreads();
    }
    if (tid < BUCKETS) bbase[tid] = s[tid] - x;   // exclusive
}

// ---------- pass B: per-bucket local sort -> final srt + offs ----------
__global__ __launch_bounds__(512) void bucketB_kernel(const int* __restrict__ cursor,
                                                      const int* __restrict__ bbase,
                                                      const int* __restrict__ tmp,
                                                      int* __restrict__ srt,
                                                      int* __restrict__ offs) {
    __shared__ int hist[512];
    __shared__ int s[512];
    __shared__ int cur[512];
    int b = blockIdx.x, tid = threadIdx.x;
    int cbase = b * CAP;
    int cnt = cursor[b] - cbase;
    int gbase = bbase[b];

    hist[tid] = 0;
    __syncthreads();
    for (int i = tid; i < cnt; i += 512) {
        int ln = tmp[cbase + i] >> 17;
        atomicAdd(&hist[ln], 1);
    }
    __syncthreads();

    int x = hist[tid];
    s[tid] = x;
    __syncthreads();
    for (int off = 1; off < 512; off <<= 1) {
        int v = (tid >= off) ? s[tid - off] : 0;
        __syncthreads();
        s[tid] += v;
        __syncthreads();
    }
    int excl = s[tid] - x;
    cur[tid] = excl;

    int node0 = b << BSHIFT;
    int nloc = min(512, N_NODES - node0);
    if (tid < nloc) offs[node0 + tid] = gbase + excl;   // coalesced
    __syncthreads();

    for (int i = tid; i < cnt; i += 512) {
        int v = tmp[cbase + i];            // L2-hot (second read)
        int ln = v >> 17;
        int p = atomicAdd(&cur[ln], 1);
        srt[gbase + p] = v & 0x1FFFF;      // scatter into 25KB L2 window
    }
}

// ---------- fused pull + linear, fp16 gather table ----------
// One wave per node (grid-stride, 8192 waves). Lane j accumulates agg[n][j]
// via an 8-wide predicated gather of fp16 rows (128 B each). Row round-trips
// through per-wave LDS; consumed as broadcast float4 against W1 row `lane`
// in 64 VGPRs:  out[n][j] = b1[j] + sum_k row[k] * W1[j*64+k].
// STORE_HALF: also emit an fp16 copy of the output row (layer 1 -> hb).
#define NBLK 2048
template <bool STORE_HALF>
__global__ __launch_bounds__(256) void fused_layer(const __half* __restrict__ h,
                                                   const int* __restrict__ offs,
                                                   const int* __restrict__ srt,
                                                   const float* __restrict__ W1,
                                                   const float* __restrict__ b1,
                                                   float* __restrict__ out,
                                                   __half* __restrict__ hb_out) {
    __shared__ __align__(16) float rowbuf[4][64];
    const int tid  = threadIdx.x;
    const int lane = tid & 63;
    const int wid  = tid >> 6;
    const int gw   = blockIdx.x * 4 + wid;
    const int GW   = NBLK * 4;

    float4 Wreg[16];
    const float4* wrow = (const float4*)(W1 + lane * D);
#pragma unroll
    for (int i = 0; i < 16; ++i) Wreg[i] = wrow[i];
    const float bj = b1[lane];

    for (int n = gw; n < N_NODES; n += GW) {
        const int beg = offs[n];
        const int end = (n == N_NODES - 1) ? N_EDGES : offs[n + 1];

        float a0 = 0.f, a1 = 0.f, a2 = 0.f, a3 = 0.f;
        for (int e = beg; e < end; e += 8) {
            // srt has an 8-entry zero pad: unclamped reads stay in-bounds
            int s0 = srt[e],     s1 = srt[e + 1], s2 = srt[e + 2], s3 = srt[e + 3];
            int s4 = srt[e + 4], s5 = srt[e + 5], s6 = srt[e + 6], s7 = srt[e + 7];
            float g0 = __half2float(h[(ll)s0 * D + lane]);
            float g1 = __half2float(h[(ll)s1 * D + lane]);
            float g2 = __half2float(h[(ll)s2 * D + lane]);
            float g3 = __half2float(h[(ll)s3 * D + lane]);
            float g4 = __half2float(h[(ll)s4 * D + lane]);
            float g5 = __half2float(h[(ll)s5 * D + lane]);
            float g6 = __half2float(h[(ll)s6 * D + lane]);
            float g7 = __half2float(h[(ll)s7 * D + lane]);
            a0 += g0;
            a1 += (e + 1 < end) ? g1 : 0.f;
            a2 += (e + 2 < end) ? g2 : 0.f;
            a3 += (e + 3 < end) ? g3 : 0.f;
            a0 += (e + 4 < end) ? g4 : 0.f;
            a1 += (e + 5 < end) ? g5 : 0.f;
            a2 += (e + 6 < end) ? g6 : 0.f;
            a3 += (e + 7 < end) ? g7 : 0.f;
        }
        const float acc = (a0 + a1) + (a2 + a3);

        rowbuf[wid][lane] = acc;           // wave-synchronous LDS transpose
        float o = bj;
        const float4* rb = (const float4*)rowbuf[wid];
#pragma unroll
        for (int k4 = 0; k4 < 16; ++k4) {
            float4 r = rb[k4];             // broadcast ds_read_b128
            o += r.x * Wreg[k4].x + r.y * Wreg[k4].y
               + r.z * Wreg[k4].z + r.w * Wreg[k4].w;
        }
        out[(ll)n * D + lane] = o;
        if (STORE_HALF) hb_out[(ll)n * D + lane] = __float2half_rn(o);
    }
}

extern "C" void kernel_launch(void* const* d_in, const int* in_sizes, int n_in,
                              void* d_out, int out_size, void* d_ws, size_t ws_size,
                              hipStream_t stream) {
    const float* x  = (const float*)d_in[0];   // [N, D]
    const int* edge = (const int*)d_in[1];     // [2, E]: src row then dst row
    const float* W1 = (const float*)d_in[2];   // [D, D]
    const float* b1 = (const float*)d_in[3];   // [D]

    const int* src = edge;
    const int* dst = edge + N_EDGES;

    float* out = (float*)d_out;                    // output 0: [N, D]
    float* hid = (float*)d_out + (ll)N_NODES * D;  // output 1: [N, D]

    // xb (fp16 x, 12.8 MB) lives in the out-region of d_out: dead scratch
    // until layer 2's final write, by which time xb is fully consumed.
    __half* xb = (__half*)d_out;

    // workspace (~18.2 MB < 25.6 MB proven): hb overlays tmp (dead after bucketB)
    char* ws = (char*)d_ws;
    int* cursor = (int*)ws;  ws += 1024;                                   // [196]
    int* bbase  = (int*)ws;  ws += 1024;                                   // [196]
    int* offs   = (int*)ws;  ws += ((size_t)N_NODES * 4 + 255) & ~255ull;  // [N]
    int* srt    = (int*)ws;  ws += ((size_t)(N_EDGES + 8) * 4 + 255) & ~255ull;  // [E+8]
    int*    tmp = (int*)ws;                    // [196*CAP] = 6.42 MB (CSR build only)
    __half* hb  = (__half*)ws;                 // [N*D] fp16 hid = 12.8 MB (after build)

    const int nbCast = (N_NODES * D / 4 + 255) / 256;

    // ---- build CSR via two-pass bucket sort (reused by both layers) ----
    init_kernel<<<1, 256, 0, stream>>>(cursor, srt);
    bucketA_kernel<<<PA_BLOCKS, 256, 0, stream>>>(src, dst, cursor, tmp);
    scanSmall_kernel<<<1, 256, 0, stream>>>(cursor, bbase);
    bucketB_kernel<<<BUCKETS, 512, 0, stream>>>(cursor, bbase, tmp, srt, offs);

    // ---- fp16 table of x (after bucketB: xb in d_out, hb frees tmp) ----
    cast_kernel<<<nbCast, 256, 0, stream>>>(x, xb);

    // ---- layer 1: hid = segsum(x) @ W1^T + b1 (also emit fp16 copy) ----
    fused_layer<true><<<NBLK, 256, 0, stream>>>(xb, offs, srt, W1, b1, hid, hb);
    // ---- layer 2: out = segsum(hid) @ W1^T + b1 ----
    fused_layer<false><<<NBLK, 256, 0, stream>>>(hb, offs, srt, W1, b1, out, nullptr);
}

// Round 7
// 287.334 us; speedup vs baseline: 1.8580x; 1.8580x over previous
//
#include <hip/hip_runtime.h>
#include <hip/hip_fp16.h>

#define N_NODES 100000
#define N_EDGES 1250000
#define D 64

#define BSHIFT 9
#define BUCKETS 196          // ceil(100000 / 512); == 4*49 exactly
#define CAP 8192             // tmp capacity per bucket (mean 6378, +22 sigma)
#define CHUNK 4096           // edges per bucketA block
#define PA_BLOCKS ((N_EDGES + CHUNK - 1) / CHUNK)   // 306
#define LCAP 64              // LDS list cap per bucket per chunk (mean 21)

typedef long long ll;

// ---------- init: cursor[b*16] = b*CAP (padded: 1 counter/cache line) ----------
__global__ void init_kernel(int* __restrict__ cursor, int* __restrict__ srt) {
    int t = threadIdx.x;
    if (t < BUCKETS) cursor[t << 4] = t * CAP;
    if (t < 8) srt[N_EDGES + t] = 0;
}

// ---------- fp32 -> fp16 cast (x -> xb), float4 granularity ----------
__global__ void cast_kernel(const float* __restrict__ in, __half* __restrict__ out) {
    int i = blockIdx.x * 256 + threadIdx.x;
    if (i < N_NODES * D / 4) {
        float4 v = ((const float4*)in)[i];
        __half2 a = __floats2half2_rn(v.x, v.y);
        __half2 b = __floats2half2_rn(v.z, v.w);
        uint2 u;
        u.x = *(const unsigned int*)&a;
        u.y = *(const unsigned int*)&b;
        ((uint2*)out)[i] = u;
    }
}

// ---------- pass A: bin edges into 196 coarse buckets ----------
// Phase 1: per-THREAD parallel reservation atomics (196 in flight per block,
// latencies overlap; padded counters = 196 independent L2 lines).
// Phase 2: wave-cooperative coalesced flush, bucket order staggered by
// blockIdx so concurrent blocks touch different lines.
__global__ __launch_bounds__(256) void bucketA_kernel(const int* __restrict__ src,
                                                      const int* __restrict__ dst,
                                                      int* __restrict__ cursor,
                                                      int* __restrict__ tmp) {
    __shared__ int lcnt[BUCKETS];
    __shared__ int gbase_s[BUCKETS];
    __shared__ int list[BUCKETS * LCAP];   // ~50 KB
    int tid = threadIdx.x;
    for (int b = tid; b < BUCKETS; b += 256) lcnt[b] = 0;
    __syncthreads();

    int base = blockIdx.x * CHUNK;
    int nE = min(CHUNK, N_EDGES - base);
    for (int i = tid; i < nE; i += 256) {
        int e = base + i;
        int s = src[e], d = dst[e];
        int b = d >> BSHIFT;
        int p = atomicAdd(&lcnt[b], 1);             // LDS atomic, cheap
        list[b * LCAP + p] = s | ((d & 511) << 17); // src:17b, dstLow:9b
    }
    __syncthreads();

    // phase 1: parallel reservation (independent atomics, overlapped latency)
    for (int b = tid; b < BUCKETS; b += 256) {
        int c = lcnt[b];
        if (c > 0) gbase_s[b] = atomicAdd(&cursor[b << 4], c);
    }
    __syncthreads();

    // phase 2: coalesced flush, staggered start
    int wave = tid >> 6, lane = tid & 63;
    const int NB = BUCKETS / 4;            // 49 buckets per wave
    int start = blockIdx.x % NB;
    for (int j = 0; j < NB; ++j) {
        int b = wave + 4 * ((start + j) % NB);
        int c = lcnt[b];
        if (c > 0) {
            int gb = gbase_s[b];
            for (int k = lane; k < c; k += 64) tmp[gb + k] = list[b * LCAP + k];
        }
    }
}

// ---------- tiny scan: bucket bases from padded cursor counts ----------
__global__ void scanSmall_kernel(const int* __restrict__ cursor, int* __restrict__ bbase) {
    __shared__ int s[256];
    int tid = threadIdx.x;
    int x = (tid < BUCKETS) ? (cursor[tid << 4] - tid * CAP) : 0;
    s[tid] = x;
    __syncthreads();
    for (int off = 1; off < 256; off <<= 1) {
        int v = (tid >= off) ? s[tid - off] : 0;
        __syncthreads();
        s[tid] += v;
        __syncthreads();
    }
    if (tid < BUCKETS) bbase[tid] = s[tid] - x;   // exclusive
}

// ---------- pass B: per-bucket local sort -> final srt + offs ----------
__global__ __launch_bounds__(512) void bucketB_kernel(const int* __restrict__ cursor,
                                                      const int* __restrict__ bbase,
                                                      const int* __restrict__ tmp,
                                                      int* __restrict__ srt,
                                                      int* __restrict__ offs) {
    __shared__ int hist[512];
    __shared__ int s[512];
    __shared__ int cur[512];
    int b = blockIdx.x, tid = threadIdx.x;
    int cbase = b * CAP;
    int cnt = cursor[b << 4] - cbase;
    int gbase = bbase[b];

    hist[tid] = 0;
    __syncthreads();
    for (int i = tid; i < cnt; i += 512) {
        int ln = tmp[cbase + i] >> 17;
        atomicAdd(&hist[ln], 1);
    }
    __syncthreads();

    int x = hist[tid];
    s[tid] = x;
    __syncthreads();
    for (int off = 1; off < 512; off <<= 1) {
        int v = (tid >= off) ? s[tid - off] : 0;
        __syncthreads();
        s[tid] += v;
        __syncthreads();
    }
    int excl = s[tid] - x;
    cur[tid] = excl;

    int node0 = b << BSHIFT;
    int nloc = min(512, N_NODES - node0);
    if (tid < nloc) offs[node0 + tid] = gbase + excl;   // coalesced
    __syncthreads();

    for (int i = tid; i < cnt; i += 512) {
        int v = tmp[cbase + i];            // L2-hot (second read)
        int ln = v >> 17;
        int p = atomicAdd(&cur[ln], 1);
        srt[gbase + p] = v & 0x1FFFF;      // scatter into 25KB L2 window
    }
}

// ---------- fused pull + linear, fp16 gather table ----------
#define NBLK 2048
template <bool STORE_HALF>
__global__ __launch_bounds__(256) void fused_layer(const __half* __restrict__ h,
                                                   const int* __restrict__ offs,
                                                   const int* __restrict__ srt,
                                                   const float* __restrict__ W1,
                                                   const float* __restrict__ b1,
                                                   float* __restrict__ out,
                                                   __half* __restrict__ hb_out) {
    __shared__ __align__(16) float rowbuf[4][64];
    const int tid  = threadIdx.x;
    const int lane = tid & 63;
    const int wid  = tid >> 6;
    const int gw   = blockIdx.x * 4 + wid;
    const int GW   = NBLK * 4;

    float4 Wreg[16];
    const float4* wrow = (const float4*)(W1 + lane * D);
#pragma unroll
    for (int i = 0; i < 16; ++i) Wreg[i] = wrow[i];
    const float bj = b1[lane];

    for (int n = gw; n < N_NODES; n += GW) {
        const int beg = offs[n];
        const int end = (n == N_NODES - 1) ? N_EDGES : offs[n + 1];

        float a0 = 0.f, a1 = 0.f, a2 = 0.f, a3 = 0.f;
        for (int e = beg; e < end; e += 8) {
            // srt has an 8-entry zero pad: unclamped reads stay in-bounds
            int s0 = srt[e],     s1 = srt[e + 1], s2 = srt[e + 2], s3 = srt[e + 3];
            int s4 = srt[e + 4], s5 = srt[e + 5], s6 = srt[e + 6], s7 = srt[e + 7];
            float g0 = __half2float(h[(ll)s0 * D + lane]);
            float g1 = __half2float(h[(ll)s1 * D + lane]);
            float g2 = __half2float(h[(ll)s2 * D + lane]);
            float g3 = __half2float(h[(ll)s3 * D + lane]);
            float g4 = __half2float(h[(ll)s4 * D + lane]);
            float g5 = __half2float(h[(ll)s5 * D + lane]);
            float g6 = __half2float(h[(ll)s6 * D + lane]);
            float g7 = __half2float(h[(ll)s7 * D + lane]);
            a0 += g0;
            a1 += (e + 1 < end) ? g1 : 0.f;
            a2 += (e + 2 < end) ? g2 : 0.f;
            a3 += (e + 3 < end) ? g3 : 0.f;
            a0 += (e + 4 < end) ? g4 : 0.f;
            a1 += (e + 5 < end) ? g5 : 0.f;
            a2 += (e + 6 < end) ? g6 : 0.f;
            a3 += (e + 7 < end) ? g7 : 0.f;
        }
        const float acc = (a0 + a1) + (a2 + a3);

        rowbuf[wid][lane] = acc;           // wave-synchronous LDS transpose
        float o = bj;
        const float4* rb = (const float4*)rowbuf[wid];
#pragma unroll
        for (int k4 = 0; k4 < 16; ++k4) {
            float4 r = rb[k4];             // broadcast ds_read_b128
            o += r.x * Wreg[k4].x + r.y * Wreg[k4].y
               + r.z * Wreg[k4].z + r.w * Wreg[k4].w;
        }
        out[(ll)n * D + lane] = o;
        if (STORE_HALF) hb_out[(ll)n * D + lane] = __float2half_rn(o);
    }
}

extern "C" void kernel_launch(void* const* d_in, const int* in_sizes, int n_in,
                              void* d_out, int out_size, void* d_ws, size_t ws_size,
                              hipStream_t stream) {
    const float* x  = (const float*)d_in[0];   // [N, D]
    const int* edge = (const int*)d_in[1];     // [2, E]: src row then dst row
    const float* W1 = (const float*)d_in[2];   // [D, D]
    const float* b1 = (const float*)d_in[3];   // [D]

    const int* src = edge;
    const int* dst = edge + N_EDGES;

    float* out = (float*)d_out;                    // output 0: [N, D]
    float* hid = (float*)d_out + (ll)N_NODES * D;  // output 1: [N, D]

    // xb (fp16 x, 12.8 MB) lives in the out-region of d_out: dead scratch
    // until layer 2's final write, by which time xb is fully consumed.
    __half* xb = (__half*)d_out;

    // workspace (~18.2 MB < 25.6 MB proven): hb overlays tmp (dead after bucketB)
    char* ws = (char*)d_ws;
    int* cursor = (int*)ws;  ws += 16384;                                  // [196*16] padded
    int* bbase  = (int*)ws;  ws += 1024;                                   // [196]
    int* offs   = (int*)ws;  ws += ((size_t)N_NODES * 4 + 255) & ~255ull;  // [N]
    int* srt    = (int*)ws;  ws += ((size_t)(N_EDGES + 8) * 4 + 255) & ~255ull;  // [E+8]
    int*    tmp = (int*)ws;                    // [196*CAP] = 6.42 MB (CSR build only)
    __half* hb  = (__half*)ws;                 // [N*D] fp16 hid = 12.8 MB (after build)

    const int nbCast = (N_NODES * D / 4 + 255) / 256;

    // ---- build CSR via two-pass bucket sort (reused by both layers) ----
    init_kernel<<<1, 256, 0, stream>>>(cursor, srt);
    bucketA_kernel<<<PA_BLOCKS, 256, 0, stream>>>(src, dst, cursor, tmp);
    scanSmall_kernel<<<1, 256, 0, stream>>>(cursor, bbase);
    bucketB_kernel<<<BUCKETS, 512, 0, stream>>>(cursor, bbase, tmp, srt, offs);

    // ---- fp16 table of x ----
    cast_kernel<<<nbCast, 256, 0, stream>>>(x, xb);

    // ---- layer 1: hid = segsum(x) @ W1^T + b1 (also emit fp16 copy) ----
    fused_layer<true><<<NBLK, 256, 0, stream>>>(xb, offs, srt, W1, b1, hid, hb);
    // ---- layer 2: out = segsum(hid) @ W1^T + b1 ----
    fused_layer<false><<<NBLK, 256, 0, stream>>>(hb, offs, srt, W1, b1, out, nullptr);
}